// Round 4
// baseline (147.251 us; speedup 1.0000x reference)
//
#include <hip/hip_runtime.h>
#include <hip/hip_bf16.h>

#define BATCH 32
#define LL 512
#define DD 768
#define EPSC 1e-5f

typedef __attribute__((ext_vector_type(8))) short bf16x8;
typedef __attribute__((ext_vector_type(4))) float f32x4;

// ---------------------------------------------------------------------------
// Kernel 1 (fused prep): for a 32-row L-slab of one batch:
//   phase 1: load X rows (fp32, coalesced float4) into LDS + compute
//            s[l] = (eps + sum_d x^2)^(1/4) in flight (64-lane shfl reduce)
//   phase 2: write Yt[b][d][l] = bf16(s[l] * x[l][d]) transposed, bf16x8.
// LDS swizzle: element (l,d) stored at d ^ 8*(l&7) ^ 16*((l>>3)&1):
//   - preserves float4 alignment/contiguity for phase-1 writes
//   - phase-2 scalar reads land exactly 2 lanes/bank (free, m136)
// ---------------------------------------------------------------------------
__global__ __launch_bounds__(256) void k_prep(const float* __restrict__ x,
                                              ushort* __restrict__ yt) {
    __shared__ float xs[32 * 768];
    __shared__ float sv[32];
    int b = blockIdx.y;
    int l0 = blockIdx.x * 32;
    int t = threadIdx.x, wave = t >> 6, lane = t & 63;
    const float* xp = x + ((size_t)b * LL + l0) * DD;

    // phase 1: 8 rows per wave, 3 float4 per lane per row
#pragma unroll
    for (int r = 0; r < 8; r++) {
        int l = wave * 8 + r;
        int sw = (8 * (l & 7)) ^ (16 * ((l >> 3) & 1));
        float sum = 0.f;
#pragma unroll
        for (int i = 0; i < 3; i++) {
            int d = lane * 4 + i * 256;
            float4 v = *(const float4*)(xp + (size_t)l * DD + d);
            sum += v.x * v.x + v.y * v.y + v.z * v.z + v.w * v.w;
            *(float4*)&xs[l * 768 + (d ^ sw)] = v;
        }
#pragma unroll
        for (int off = 32; off > 0; off >>= 1)
            sum += __shfl_xor(sum, off, 64);
        if (lane == 0) sv[l] = sqrtf(sqrtf(EPSC + sum));
    }
    __syncthreads();

    // phase 2: transposed bf16 write. lane covers (d = it*64 + t>>2, l-chunk t&3)
    ushort* yp = yt + (size_t)b * DD * LL + l0;
    int lc = t & 3, d0 = t >> 2;
#pragma unroll
    for (int it = 0; it < 12; it++) {
        int d = it * 64 + d0;
        bf16x8 w;
#pragma unroll
        for (int j = 0; j < 8; j++) {
            int l = lc * 8 + j;
            int sw = (8 * (l & 7)) ^ (16 * ((l >> 3) & 1));
            float v = xs[l * 768 + (d ^ sw)] * sv[l];
            __hip_bfloat16 h = __float2bfloat16(v);
            w[j] = *(short*)&h;
        }
        *(bf16x8*)(yp + (size_t)d * LL + lc * 8) = w;
    }
}

// ---------------------------------------------------------------------------
// Kernel 2: C[b] = Yt[b] * Yt[b]^T, symmetric -> 21 upper-tri 128x128 blocks
// per batch, XCD-swizzled. Gray-code chunk swizzle on the staged LDS rows:
// row m's 8-elem chunk c lives at slot c ^ ((m^(m>>1))&3), so the b128
// fragment reads hit each bank exactly 2x (free) instead of 8-way.
// ---------------------------------------------------------------------------
__global__ __launch_bounds__(256) void k_gemm(const ushort* __restrict__ yt,
                                              float* __restrict__ out) {
    __shared__ ushort At[128 * 32];                   // [m][k-chunks swizzled]
    __shared__ ushort Bt[128 * 32];
    int i = blockIdx.x;                               // [0, 672)
    int xcd = i & 7, slot = i >> 3;                   // XCD round-robin
    int b = xcd + 8 * (slot / 21);
    int p = slot % 21;
    int t = p, tm = 0, rem = 6;
    while (t >= rem) { t -= rem; rem--; tm++; }
    int tn = tm + t;                                  // tm <= tn
    bool diag = (tm == tn);
    int m0 = tm * 128, n0 = tn * 128;
    int tid = threadIdx.x;
    int wave = tid >> 6, lane = tid & 63;
    int wr = wave >> 1, wc = wave & 1;
    const ushort* yb = yt + (size_t)b * DD * LL;

    f32x4 acc[4][4];
#pragma unroll
    for (int ii = 0; ii < 4; ii++)
#pragma unroll
        for (int j = 0; j < 4; j++) acc[ii][j] = (f32x4){0.f, 0.f, 0.f, 0.f};

    // staging: lane -> row srow, LDS slot lane&3; source chunk gray-swizzled
    int srow = lane >> 2;
    int ssw = (srow ^ (srow >> 1)) & 3;
    int scol = (((lane & 3) ^ ssw)) * 8;
    // frag read: logical chunk q=lane>>4 lives at slot q ^ gray(row&15)
    int fr = lane & 15;
    int fsw = (fr ^ (fr >> 1)) & 3;
    int fslot = (lane >> 4) ^ fsw;

    for (int ks = 0; ks < 16; ks++) {
        int k0 = ks * 32;
        __syncthreads();
#pragma unroll
        for (int c = 0; c < 2; c++) {
            int rloc = wave * 32 + c * 16 + srow;
            const ushort* gA = yb + (size_t)(m0 + rloc) * LL + k0 + scol;
            __builtin_amdgcn_global_load_lds(
                (const __attribute__((address_space(1))) void*)gA,
                (__attribute__((address_space(3))) void*)(At + (wave * 32 + c * 16) * 32),
                16, 0, 0);
            if (!diag) {
                const ushort* gB = yb + (size_t)(n0 + rloc) * LL + k0 + scol;
                __builtin_amdgcn_global_load_lds(
                    (const __attribute__((address_space(1))) void*)gB,
                    (__attribute__((address_space(3))) void*)(Bt + (wave * 32 + c * 16) * 32),
                    16, 0, 0);
            }
        }
        __syncthreads();

        const ushort* Bsrc = diag ? At : Bt;
        bf16x8 afrag[4], bfrag[4];
#pragma unroll
        for (int ii = 0; ii < 4; ii++) {
            int m = wr * 64 + ii * 16 + fr;
            afrag[ii] = *(const bf16x8*)(At + m * 32 + fslot * 8);
            int n = wc * 64 + ii * 16 + fr;
            bfrag[ii] = *(const bf16x8*)(Bsrc + n * 32 + fslot * 8);
        }
#pragma unroll
        for (int ii = 0; ii < 4; ii++)
#pragma unroll
            for (int j = 0; j < 4; j++)
                acc[ii][j] = __builtin_amdgcn_mfma_f32_16x16x32_bf16(
                    afrag[ii], bfrag[j], acc[ii][j], 0, 0, 0);
    }

    // Epilogue. C/D layout: col = lane&15, row = (lane>>4)*4 + r.
    // Transposed view: a lane's 4 regs are 4 consecutive columns -> float4.
    float* op = out + (size_t)b * DD * DD;
#pragma unroll
    for (int ii = 0; ii < 4; ii++) {
        int colb = m0 + wr * 64 + ii * 16 + (lane >> 4) * 4;
#pragma unroll
        for (int j = 0; j < 4; j++) {
            int row = n0 + wc * 64 + j * 16 + (lane & 15);
            float4 v = {acc[ii][j][0], acc[ii][j][1], acc[ii][j][2], acc[ii][j][3]};
            *(float4*)(op + (size_t)row * DD + colb) = v;   // mirror (or diag)
        }
    }
    if (!diag) {
#pragma unroll
        for (int ii = 0; ii < 4; ii++) {
            int mbase = m0 + wr * 64 + ii * 16 + (lane >> 4) * 4;
#pragma unroll
            for (int j = 0; j < 4; j++) {
                int n = n0 + wc * 64 + j * 16 + (lane & 15);
#pragma unroll
                for (int r = 0; r < 4; r++)
                    op[(size_t)(mbase + r) * DD + n] = acc[ii][j][r];
            }
        }
    }
}

// ---------------------------------------------------------------------------
extern "C" void kernel_launch(void* const* d_in, const int* in_sizes, int n_in,
                              void* d_out, int out_size, void* d_ws, size_t ws_size,
                              hipStream_t stream) {
    const float* x = (const float*)d_in[0];
    ushort* yt = (ushort*)d_ws;                       // 25.2 MB bf16

    k_prep<<<dim3(LL / 32, BATCH), 256, 0, stream>>>(x, yt);
    k_gemm<<<dim3(21 * BATCH), 256, 0, stream>>>(yt, (float*)d_out);
}

// Round 5
// 135.812 us; speedup vs baseline: 1.0842x; 1.0842x over previous
//
#include <hip/hip_runtime.h>
#include <hip/hip_bf16.h>

#define BATCH 32
#define LL 512
#define DD 768
#define EPSC 1e-5f

typedef __attribute__((ext_vector_type(8))) short bf16x8;
typedef __attribute__((ext_vector_type(4))) float f32x4;

// ---------------------------------------------------------------------------
// Kernel 1: per-row scale s[b*L+l] = (eps + sum_d x^2)^(1/4)
// One wave per row (768 = 64 lanes * 3 float4).
// ---------------------------------------------------------------------------
__global__ __launch_bounds__(256) void k_scales(const float* __restrict__ x,
                                                float* __restrict__ s) {
    int wave = threadIdx.x >> 6;
    int lane = threadIdx.x & 63;
    int row = blockIdx.x * 4 + wave;                 // [0, 16384)
    const float4* xr = (const float4*)(x + (size_t)row * DD);
    float sum = 0.f;
#pragma unroll
    for (int i = 0; i < 3; i++) {
        float4 v = xr[lane + i * 64];
        sum += v.x * v.x + v.y * v.y + v.z * v.z + v.w * v.w;
    }
#pragma unroll
    for (int off = 32; off > 0; off >>= 1)
        sum += __shfl_xor(sum, off, 64);
    if (lane == 0) s[row] = sqrtf(sqrtf(EPSC + sum));
}

// ---------------------------------------------------------------------------
// Kernel 2: Yt[b][d][l] = bf16( s[b][l] * x[b][l][d] )   (transpose via LDS)
// 64x64 tile, row stride 65 floats -> both phases bank-conflict-free.
// ---------------------------------------------------------------------------
__global__ __launch_bounds__(256) void k_transpose(const float* __restrict__ x,
                                                   const float* __restrict__ s,
                                                   ushort* __restrict__ yt) {
    __shared__ float tile[64][65];
    __shared__ float svec[64];
    int b = blockIdx.z;
    int l0 = blockIdx.y * 64;
    int d0 = blockIdx.x * 64;
    int t = threadIdx.x;
    if (t < 64) svec[t] = s[b * LL + l0 + t];
    const float* xp = x + ((size_t)b * LL + l0) * DD + d0;
    int f = t & 15, lr0 = t >> 4;                     // f: float4 col, lr0: row
#pragma unroll
    for (int r = 0; r < 4; r++) {
        int l = lr0 + r * 16;
        float4 v = *(const float4*)(xp + (size_t)l * DD + f * 4);
#pragma unroll
        for (int j = 0; j < 4; j++)
            tile[l][f * 4 + j] = ((const float*)&v)[j];
    }
    __syncthreads();
    ushort* yp = yt + ((size_t)b * DD + d0) * LL + l0;
    int lc = t & 7, dl0 = t >> 3;                     // lc: l-chunk, dl0: d row
#pragma unroll
    for (int it = 0; it < 2; it++) {
        int d = dl0 + it * 32;
        bf16x8 w;
#pragma unroll
        for (int j = 0; j < 8; j++) {
            int l = lc * 8 + j;
            float v = tile[l][d] * svec[l];
            __hip_bfloat16 h = __float2bfloat16(v);
            w[j] = *(short*)&h;
        }
        *(bf16x8*)(yp + (size_t)d * LL + lc * 8) = w;
    }
}

// ---------------------------------------------------------------------------
// Kernel 3: C[b] = Yt[b]*Yt[b]^T, symmetric. 64x64 tiles: 78 upper-tri pairs
// per batch x 32 = 2496 blocks (9.75/CU) -- attacks the measured 15%
// occupancy of the 128-tile version (672 blocks was the limiter).
// XCD swizzle keeps each batch's 786 KB Yt in one XCD's L2.
// Gray-code chunk swizzle keeps b128 frag reads at 2 lanes/bank (free).
// ---------------------------------------------------------------------------
__global__ __launch_bounds__(256) void k_gemm(const ushort* __restrict__ yt,
                                              float* __restrict__ out) {
    __shared__ ushort At[64 * 32];                    // 4 KB, [m][k-chunks swz]
    __shared__ ushort Bt[64 * 32];
    int i = blockIdx.x;                               // [0, 2496)
    int xcd = i & 7, slot = i >> 3;                   // XCD round-robin
    int b = xcd + 8 * (slot / 78);
    int p = slot % 78;
    int t = p, tm = 0, rem = 12;
    while (t >= rem) { t -= rem; rem--; tm++; }
    int tn = tm + t;                                  // tm <= tn
    bool diag = (tm == tn);
    int m0 = tm * 64, n0 = tn * 64;
    int tid = threadIdx.x;
    int wave = tid >> 6, lane = tid & 63;
    int wr = wave >> 1, wc = wave & 1;                // 2x2 waves, 32x32 each
    const ushort* yb = yt + (size_t)b * DD * LL;

    f32x4 acc[2][2];
#pragma unroll
    for (int ii = 0; ii < 2; ii++)
#pragma unroll
        for (int j = 0; j < 2; j++) acc[ii][j] = (f32x4){0.f, 0.f, 0.f, 0.f};

    // staging: wave stages rows wave*16 + (lane>>2); chunk gray-swizzled
    int srow = lane >> 2;
    int ssw = (srow ^ (srow >> 1)) & 3;
    int scol = ((lane & 3) ^ ssw) * 8;
    // frag read: logical chunk q=lane>>4 lives at slot q ^ gray(row&15)
    int fr = lane & 15;
    int fsw = (fr ^ (fr >> 1)) & 3;
    int fslot = (lane >> 4) ^ fsw;

    for (int ks = 0; ks < 16; ks++) {
        int k0 = ks * 32;
        __syncthreads();
        {
            int rloc = wave * 16 + srow;
            const ushort* gA = yb + (size_t)(m0 + rloc) * LL + k0 + scol;
            __builtin_amdgcn_global_load_lds(
                (const __attribute__((address_space(1))) void*)gA,
                (__attribute__((address_space(3))) void*)(At + (wave * 16) * 32),
                16, 0, 0);
            if (!diag) {
                const ushort* gB = yb + (size_t)(n0 + rloc) * LL + k0 + scol;
                __builtin_amdgcn_global_load_lds(
                    (const __attribute__((address_space(1))) void*)gB,
                    (__attribute__((address_space(3))) void*)(Bt + (wave * 16) * 32),
                    16, 0, 0);
            }
        }
        __syncthreads();

        const ushort* Bsrc = diag ? At : Bt;
        bf16x8 afrag[2], bfrag[2];
#pragma unroll
        for (int ii = 0; ii < 2; ii++) {
            int m = wr * 32 + ii * 16 + fr;
            afrag[ii] = *(const bf16x8*)(At + m * 32 + fslot * 8);
            int n = wc * 32 + ii * 16 + fr;
            bfrag[ii] = *(const bf16x8*)(Bsrc + n * 32 + fslot * 8);
        }
#pragma unroll
        for (int ii = 0; ii < 2; ii++)
#pragma unroll
            for (int j = 0; j < 2; j++)
                acc[ii][j] = __builtin_amdgcn_mfma_f32_16x16x32_bf16(
                    afrag[ii], bfrag[j], acc[ii][j], 0, 0, 0);
    }

    // Epilogue. C/D layout: col = lane&15, row = (lane>>4)*4 + r.
    // Mirror (transposed) write is float4; direct write scalar (off-diag).
    float* op = out + (size_t)b * DD * DD;
#pragma unroll
    for (int ii = 0; ii < 2; ii++) {
        int colb = m0 + wr * 32 + ii * 16 + (lane >> 4) * 4;
#pragma unroll
        for (int j = 0; j < 2; j++) {
            int row = n0 + wc * 32 + j * 16 + fr;
            float4 v = {acc[ii][j][0], acc[ii][j][1], acc[ii][j][2], acc[ii][j][3]};
            *(float4*)(op + (size_t)row * DD + colb) = v;   // mirror (or diag)
        }
    }
    if (!diag) {
#pragma unroll
        for (int ii = 0; ii < 2; ii++) {
            int mbase = m0 + wr * 32 + ii * 16 + (lane >> 4) * 4;
#pragma unroll
            for (int j = 0; j < 2; j++) {
                int n = n0 + wc * 32 + j * 16 + fr;
#pragma unroll
                for (int r = 0; r < 4; r++)
                    op[(size_t)(mbase + r) * DD + n] = acc[ii][j][r];
            }
        }
    }
}

// ---------------------------------------------------------------------------
extern "C" void kernel_launch(void* const* d_in, const int* in_sizes, int n_in,
                              void* d_out, int out_size, void* d_ws, size_t ws_size,
                              hipStream_t stream) {
    const float* x = (const float*)d_in[0];
    float* s = (float*)d_ws;                                        // 64 KB
    ushort* yt = (ushort*)((char*)d_ws + 65536);                    // 25.2 MB bf16

    k_scales<<<dim3((BATCH * LL) / 4), 256, 0, stream>>>(x, s);
    k_transpose<<<dim3(DD / 64, LL / 64, BATCH), 256, 0, stream>>>(x, s, yt);
    k_gemm<<<dim3(78 * BATCH), 256, 0, stream>>>(yt, (float*)d_out);
}